// Round 1
// baseline (3393.055 us; speedup 1.0000x reference)
//
#include <hip/hip_runtime.h>
#include <hip/hip_bf16.h>

// LSS voxel pooling:
//   x:    (B=8, N=6, D=41, H=16, W=44, C=64) f32   -> 88,670,208 elems
//   geom: (B, N, D, H, W, 3) f32                   ->  4,156,416 elems
//   out:  (B, C=64, X=200, Y=200) f32              -> 20,480,000 elems
//
// Binning (must bit-match reference fp32 math):
//   ix = trunc((gx - (-50)) / 0.5)   kept if 0 <= ix < 200
//   iy = trunc((gy - (-50)) / 0.5)   kept if 0 <= iy < 200
//   iz = trunc((gz - (-10)) / 20)    kept if iz == 0
//   out[b][c][ix][iy] += x[p][c]

#define NP_TOTAL 1385472
#define NP_PER_B 173184   // N*D*H*W = 6*41*16*44
#define NXY      200

__global__ void lss_scatter_atomic(const float* __restrict__ x,
                                   const float* __restrict__ geom,
                                   float* __restrict__ out) {
    const int lane   = threadIdx.x & 63;
    const int wave   = (blockIdx.x * blockDim.x + threadIdx.x) >> 6;
    const int nwaves = (gridDim.x * blockDim.x) >> 6;

    for (int p = wave; p < NP_TOTAL; p += nwaves) {
        // wave-uniform: all lanes load same 3 floats (coalesced broadcast)
        const float gx = geom[(size_t)p * 3 + 0];
        const float gy = geom[(size_t)p * 3 + 1];
        const float gz = geom[(size_t)p * 3 + 2];

        // IEEE fp32 division + C trunc-toward-zero (matches .astype(int32))
        const int ix = (int)((gx + 50.0f) / 0.5f);
        const int iy = (int)((gy + 50.0f) / 0.5f);
        const int iz = (int)((gz + 10.0f) / 20.0f);

        if (ix >= 0 && ix < NXY && iy >= 0 && iy < NXY && iz == 0) {
            const int b = p / NP_PER_B;
            const float v = x[(size_t)p * 64 + lane];  // coalesced 256B/wave
            // out[b][c=lane][ix][iy]
            atomicAdd(&out[(((size_t)b * 64 + lane) * NXY + ix) * NXY + iy], v);
        }
    }
}

extern "C" void kernel_launch(void* const* d_in, const int* in_sizes, int n_in,
                              void* d_out, int out_size, void* d_ws, size_t ws_size,
                              hipStream_t stream) {
    const float* x    = (const float*)d_in[0];
    const float* geom = (const float*)d_in[1];
    float* out = (float*)d_out;

    // output is accumulated into -> must start at zero every call
    hipMemsetAsync(out, 0, (size_t)out_size * sizeof(float), stream);

    const int block = 256;               // 4 waves/block
    const int grid  = 2048;              // 8192 waves, ~169 points each
    lss_scatter_atomic<<<grid, block, 0, stream>>>(x, geom, out);
}

// Round 2
// 625.925 us; speedup vs baseline: 5.4209x; 5.4209x over previous
//
#include <hip/hip_runtime.h>
#include <hip/hip_bf16.h>

// LSS voxel pooling via inverted index (BEVPool-style), no float atomics.
//   x:    (B=8, N=6, D=41, H=16, W=44, C=64) f32
//   geom: (B, N, D, H, W, 3) f32
//   out:  (B, C=64, X=200, Y=200) f32
//
// bin = (b*200 + ix)*200 + iy,  kept iff 0<=ix<200, 0<=iy<200, iz==0
// (IEEE fp32 add + div + trunc-toward-zero matches reference .astype(int32))

#define NP        1385472
#define NP_PER_B  173184      // N*D*H*W
#define NXY       200
#define NBIN      320000      // 8*200*200
#define NBLK_SCAN 1250        // NBIN/256 exactly

// ---------------- phase A: bin each point + histogram ----------------
__global__ void bin_points(const float* __restrict__ geom,
                           int* __restrict__ bins,
                           int* __restrict__ counts) {
    int p = blockIdx.x * 256 + threadIdx.x;
    if (p >= NP) return;
    float gx = geom[(size_t)p * 3 + 0];
    float gy = geom[(size_t)p * 3 + 1];
    float gz = geom[(size_t)p * 3 + 2];
    int ix = (int)((gx + 50.0f) / 0.5f);
    int iy = (int)((gy + 50.0f) / 0.5f);
    int iz = (int)((gz + 10.0f) / 20.0f);
    int bin = -1;
    if (ix >= 0 && ix < NXY && iy >= 0 && iy < NXY && iz == 0) {
        int b = p / NP_PER_B;
        bin = (b * NXY + ix) * NXY + iy;
        atomicAdd(&counts[bin], 1);
    }
    bins[p] = bin;
}

// ---------------- phase B: exclusive scan of counts ----------------
__global__ void scan_blocks(const int* __restrict__ counts,
                            int* __restrict__ offsets,
                            int* __restrict__ blocksums) {
    __shared__ int tmp[256];
    int i = blockIdx.x * 256 + threadIdx.x;
    int v = (i < NBIN) ? counts[i] : 0;
    tmp[threadIdx.x] = v;
    __syncthreads();
    for (int d = 1; d < 256; d <<= 1) {
        int t = (threadIdx.x >= d) ? tmp[threadIdx.x - d] : 0;
        __syncthreads();
        tmp[threadIdx.x] += t;
        __syncthreads();
    }
    if (i < NBIN) offsets[i] = tmp[threadIdx.x] - v;   // exclusive
    if (threadIdx.x == 255) blocksums[blockIdx.x] = tmp[255];
}

__global__ void scan_sums(int* __restrict__ blocksums, int nblocks) {
    __shared__ int tmp[256];
    __shared__ int carry;
    if (threadIdx.x == 0) carry = 0;
    __syncthreads();
    for (int base = 0; base < nblocks; base += 256) {
        int i = base + threadIdx.x;
        int v = (i < nblocks) ? blocksums[i] : 0;
        tmp[threadIdx.x] = v;
        __syncthreads();
        for (int d = 1; d < 256; d <<= 1) {
            int t = (threadIdx.x >= d) ? tmp[threadIdx.x - d] : 0;
            __syncthreads();
            tmp[threadIdx.x] += t;
            __syncthreads();
        }
        if (i < nblocks) blocksums[i] = tmp[threadIdx.x] - v + carry;  // exclusive
        __syncthreads();
        if (threadIdx.x == 255) carry += tmp[255];
        __syncthreads();
    }
}

__global__ void add_block_offsets(int* __restrict__ offsets,
                                  const int* __restrict__ blocksums) {
    int i = blockIdx.x * 256 + threadIdx.x;
    if (i < NBIN) offsets[i] += blocksums[blockIdx.x];
}

// ---------------- phase C: scatter point indices into CSR ----------------
__global__ void scatter_idx(const int* __restrict__ bins,
                            const int* __restrict__ offsets,
                            int* __restrict__ cursor,
                            int* __restrict__ sorted) {
    int p = blockIdx.x * 256 + threadIdx.x;
    if (p >= NP) return;
    int bin = bins[p];
    if (bin >= 0) {
        int pos = atomicAdd(&cursor[bin], 1);
        sorted[offsets[bin] + pos] = p;
    }
}

// ---------------- phase D: gather + coalesced write ----------------
// block = one (b, ix) row = 200 bins; 4 waves, wave handles iy = w, w+4, ...
// lane = channel. Results staged in padded LDS tile then written coalesced.
__global__ __launch_bounds__(256) void gather(const float* __restrict__ x,
                                              const int* __restrict__ offsets,
                                              const int* __restrict__ counts,
                                              const int* __restrict__ sorted,
                                              float* __restrict__ out) {
    __shared__ float tile[64 * 201];   // [c][iy], pad 201 to kill bank conflicts
    const int bix  = blockIdx.x;       // b*200 + ix
    const int wave = threadIdx.x >> 6;
    const int lane = threadIdx.x & 63;

    for (int iy = wave; iy < NXY; iy += 4) {
        const int bin   = bix * NXY + iy;
        const int start = offsets[bin];
        const int len   = counts[bin];
        float acc = 0.0f;
        for (int k = 0; k < len; ++k) {
            const int pid = sorted[start + k];              // wave-uniform
            acc += x[(size_t)pid * 64 + lane];              // coalesced 256B
        }
        tile[lane * 201 + iy] = acc;
    }
    __syncthreads();

    const int b  = bix / NXY;
    const int ix = bix % NXY;
    float* obase = out + (size_t)b * 64 * 40000 + (size_t)ix * 200;
    for (int f = threadIdx.x; f < 64 * NXY; f += 256) {
        const int c  = f / NXY;
        const int iy = f % NXY;
        obase[(size_t)c * 40000 + iy] = tile[c * 201 + iy];
    }
}

// ---------------- fallback (round-1): direct atomic scatter ----------------
__global__ void lss_scatter_atomic(const float* __restrict__ x,
                                   const float* __restrict__ geom,
                                   float* __restrict__ out) {
    const int lane   = threadIdx.x & 63;
    const int wave   = (blockIdx.x * blockDim.x + threadIdx.x) >> 6;
    const int nwaves = (gridDim.x * blockDim.x) >> 6;
    for (int p = wave; p < NP; p += nwaves) {
        const float gx = geom[(size_t)p * 3 + 0];
        const float gy = geom[(size_t)p * 3 + 1];
        const float gz = geom[(size_t)p * 3 + 2];
        const int ix = (int)((gx + 50.0f) / 0.5f);
        const int iy = (int)((gy + 50.0f) / 0.5f);
        const int iz = (int)((gz + 10.0f) / 20.0f);
        if (ix >= 0 && ix < NXY && iy >= 0 && iy < NXY && iz == 0) {
            const int b = p / NP_PER_B;
            const float v = x[(size_t)p * 64 + lane];
            atomicAdd(&out[(((size_t)b * 64 + lane) * NXY + ix) * NXY + iy], v);
        }
    }
}

extern "C" void kernel_launch(void* const* d_in, const int* in_sizes, int n_in,
                              void* d_out, int out_size, void* d_ws, size_t ws_size,
                              hipStream_t stream) {
    const float* x    = (const float*)d_in[0];
    const float* geom = (const float*)d_in[1];
    float* out = (float*)d_out;

    // workspace carve-up
    char* ws = (char*)d_ws;
    size_t off = 0;
    int* counts    = (int*)(ws + off); off += (size_t)NBIN * 4;
    int* offsets   = (int*)(ws + off); off += (size_t)NBIN * 4;
    int* cursor    = (int*)(ws + off); off += (size_t)NBIN * 4;
    int* blocksums = (int*)(ws + off); off += (size_t)NBLK_SCAN * 4;
    int* bins      = (int*)(ws + off); off += (size_t)NP * 4;
    int* sorted    = (int*)(ws + off); off += (size_t)NP * 4;

    if (ws_size < off) {
        // fallback: direct atomic scatter
        hipMemsetAsync(out, 0, (size_t)out_size * sizeof(float), stream);
        lss_scatter_atomic<<<2048, 256, 0, stream>>>(x, geom, out);
        return;
    }

    hipMemsetAsync(counts, 0, (size_t)NBIN * 4, stream);
    hipMemsetAsync(cursor, 0, (size_t)NBIN * 4, stream);

    const int pblocks = (NP + 255) / 256;                 // 5412
    bin_points<<<pblocks, 256, 0, stream>>>(geom, bins, counts);
    scan_blocks<<<NBLK_SCAN, 256, 0, stream>>>(counts, offsets, blocksums);
    scan_sums<<<1, 256, 0, stream>>>(blocksums, NBLK_SCAN);
    add_block_offsets<<<NBLK_SCAN, 256, 0, stream>>>(offsets, blocksums);
    scatter_idx<<<pblocks, 256, 0, stream>>>(bins, offsets, cursor, sorted);
    gather<<<8 * NXY, 256, 0, stream>>>(x, offsets, counts, sorted, out);
}